// Round 3
// baseline (933.967 us; speedup 1.0000x reference)
//
#include <hip/hip_runtime.h>

// V=5000, C=128, K=64. Solve op'(W^) = R^ in the Mx-congruence basis:
// op'(W)_ab = (G^ W H)_ab + LMB * sum_k W_ak H_kb [pr_ak pr_ab + pi_ak pi_ab]
// pr_ak = r1r_a - d2r_k, pi_ak = r1i_a - d2i_k, G^ = Mx^T (A A^T) Mx.
#define NV 5000
#define LMB 100.0f
#define MAXIT 150

// float offsets in workspace
#define A_OFF    0
#define B0_OFF   8192
#define BC_OFF   16384
#define H_OFF    24576
#define G_OFF    28672
#define GH_OFF   32768
#define PR_OFF   36864
#define PI_OFF   40960
#define RH_OFF   45312
#define ZG_OFF   49408
#define XG_OFF   53504
#define CTRL_OFF 57600   // [0..63] cnt ints; rz floats at +64; pq floats at +224
#define LR_OFF   58112   // Linv row-major, 64 * 4096
#define LT_OFF   320256  // Linv col-major (transposed), 64 * 4096
#define WS_NEED  582400

__device__ __forceinline__ float aload(const float* p) {
  return __hip_atomic_load(p, __ATOMIC_RELAXED, __HIP_MEMORY_SCOPE_AGENT);
}
__device__ __forceinline__ void astore(float* p, float v) {
  __hip_atomic_store(p, v, __ATOMIC_RELAXED, __HIP_MEMORY_SCOPE_AGENT);
}

__global__ void zero_kernel(float* p, int n) {
  int e = blockIdx.x * 256 + threadIdx.x;
  if (e < n) p[e] = 0.f;
}

// ---------------- A += Px fx, B0 += Py fy : split-K (40 chunks of 125), LDS-staged ----------------
__global__ __launch_bounds__(256) void proj2_kernel(const float* Px, const float* fx,
                                                    const float* Py, const float* fy,
                                                    float* A, float* B0) {
  int b = blockIdx.x;
  int mat = b & 1, chunk = b >> 1;
  const float* P = mat ? Py : Px;
  const float* f = mat ? fy : fx;
  float* O = mat ? B0 : A;
  int v0 = chunk * 125;
  __shared__ float Pl[125 * 65];
  int tid = threadIdx.x, lane = tid & 63, wv = tid >> 6;
  for (int ii = wv; ii < 64; ii += 4)
    for (int vv = lane; vv < 125; vv += 64)
      Pl[vv * 65 + ii] = P[ii * NV + v0 + vv];
  __syncthreads();
  int c = tid & 127, half = tid >> 7;
  float acc[32];
#pragma unroll
  for (int u = 0; u < 32; ++u) acc[u] = 0.f;
  for (int v = 0; v < 125; ++v) {
    float fv = f[(v0 + v) * 128 + c];
    const float* pl = Pl + v * 65 + half * 32;
#pragma unroll
    for (int u = 0; u < 32; ++u) acc[u] = fmaf(pl[u], fv, acc[u]);
  }
  for (int u = 0; u < 32; ++u) atomicAdd(&O[(half * 32 + u) * 128 + c], acc[u]);
}

// ---------------- Bc = My B0 | H = My^T My | G = A A^T | scal + Pr/Pi ----------------
__global__ __launch_bounds__(256) void prep1_kernel(const float* A, const float* B0, const float* My,
                                                    const float* ex, const float* ey,
                                                    float* Bc, float* H, float* G,
                                                    float* PR, float* PI) {
  int q = blockIdx.x, tid = threadIdx.x;
  if (q == 0) {
    for (int idx = tid; idx < 8192; idx += 256) {
      int i = idx >> 7, c = idx & 127;
      float acc = 0.f;
      for (int j = 0; j < 64; ++j) acc = fmaf(My[i * 64 + j], B0[j * 128 + c], acc);
      Bc[idx] = acc;
    }
  } else if (q == 1) {
    for (int idx = tid; idx < 4096; idx += 256) {
      int i = idx >> 6, j = idx & 63;
      float acc = 0.f;
      for (int t = 0; t < 64; ++t) acc = fmaf(My[t * 64 + i], My[t * 64 + j], acc);
      H[idx] = acc;
    }
  } else if (q == 2) {
    for (int idx = tid; idx < 4096; idx += 256) {
      int i = idx >> 6, j = idx & 63;
      float acc = 0.f;
      for (int c = 0; c < 128; ++c) acc = fmaf(A[i * 128 + c], A[j * 128 + c], acc);
      G[idx] = acc;
    }
  } else {
    __shared__ float vs[256];
    if (tid < 64) {
      float vx = ex[tid], vy = ey[tid];
      float m = fmaxf(vx, vy);
#pragma unroll
      for (int o = 32; o > 0; o >>= 1) m = fmaxf(m, __shfl_xor(m, o, 64));
      float g1 = sqrtf(vx / m), g2 = sqrtf(vy / m);   // GAMMA = 0.5
      float d1 = 1.f / fmaf(g1, g1, 1.f), d2 = 1.f / fmaf(g2, g2, 1.f);
      vs[tid] = g1 * d1; vs[64 + tid] = d1;           // r1r, r1i
      vs[128 + tid] = g2 * d2; vs[192 + tid] = d2;    // d2r, d2i
    }
    __syncthreads();
    for (int e = tid; e < 4096; e += 256) {
      int a = e >> 6, k = e & 63;
      PR[e] = vs[a] - vs[128 + k];
      PI[e] = vs[64 + a] - vs[192 + k];
    }
  }
}

// ---------------- GH = Mx^T G Mx | RH = Mx^T (A Bc^T) My ----------------
__global__ __launch_bounds__(256) void prep2_kernel(const float* A, const float* Bc, const float* Mx,
                                                    const float* My, const float* G,
                                                    float* GH, float* RH) {
  __shared__ float sm[64 * 129 + 64 * 65];
  int tid = threadIdx.x;
  if (blockIdx.x == 0) {
    float* Ts = sm;  // [64][65]
    for (int idx = tid; idx < 4096; idx += 256) {
      int i = idx >> 6, j = idx & 63;
      float acc = 0.f;
      for (int t = 0; t < 64; ++t) acc = fmaf(Mx[t * 64 + i], G[t * 64 + j], acc);
      Ts[i * 65 + j] = acc;
    }
    __syncthreads();
    for (int idx = tid; idx < 4096; idx += 256) {
      int i = idx >> 6, j = idx & 63;
      float acc = 0.f;
      for (int t = 0; t < 64; ++t) acc = fmaf(Ts[i * 65 + t], Mx[t * 64 + j], acc);
      GH[idx] = acc;
    }
  } else {
    float* Bs = sm;              // [64][129]
    float* Zs = sm + 64 * 129;   // [64][65]
    for (int e = tid; e < 8192; e += 256) Bs[(e >> 7) * 129 + (e & 127)] = Bc[e];
    __syncthreads();
    for (int idx = tid; idx < 4096; idx += 256) {
      int i = idx >> 6, j = idx & 63;
      float acc = 0.f;
      for (int c = 0; c < 128; ++c) acc = fmaf(A[i * 128 + c], Bs[j * 129 + c], acc);
      Zs[i * 65 + j] = acc;
    }
    __syncthreads();
    float* T2 = sm;  // reuse Bs region
    for (int idx = tid; idx < 4096; idx += 256) {
      int i = idx >> 6, j = idx & 63;
      float acc = 0.f;
      for (int t = 0; t < 64; ++t) acc = fmaf(Mx[t * 64 + i], Zs[t * 65 + j], acc);
      T2[i * 65 + j] = acc;
    }
    __syncthreads();
    for (int idx = tid; idx < 4096; idx += 256) {
      int i = idx >> 6, j = idx & 63;
      float acc = 0.f;
      for (int t = 0; t < 64; ++t) acc = fmaf(T2[i * 65 + t], My[t * 64 + j], acc);
      RH[idx] = acc;
    }
  }
}

// ---------------- per-row exact blocks: B_a = G^_aa H + LMB(Dra H Dra + Dia H Dia); Linv ----------------
__global__ __launch_bounds__(256) void blockchol_kernel(const float* H, const float* GH,
                                                        const float* PR, const float* PI,
                                                        float* LR, float* LT, float* ctrl) {
  int a = blockIdx.x, tid = threadIdx.x;
  if (a == 0) for (int e = tid; e < 512; e += 256) ctrl[e] = 0.f;
  __shared__ float M[64][65];
  __shared__ float T[64][65];
  __shared__ float pra[64], pia[64];
  if (tid < 64) { pra[tid] = PR[a * 64 + tid]; pia[tid] = PI[a * 64 + tid]; }
  __syncthreads();
  float gaa = GH[a * 64 + a];
  for (int e = tid; e < 4096; e += 256) {
    int k = e >> 6, b = e & 63;
    M[k][b] = H[e] * (gaa + LMB * (pra[k] * pra[b] + pia[k] * pia[b]));
    T[k][b] = 0.f;
  }
  __syncthreads();
  for (int j = 0; j < 64; ++j) {
    float pv = M[j][j];
    __syncthreads();
    float sc = rsqrtf(pv);
    if (tid < 64 - j) M[j + tid][j] *= sc;
    __syncthreads();
    int m = 63 - j, cnt2 = (m * (m + 1)) >> 1;
    for (int e = tid; e < cnt2; e += 256) {
      int rp = (int)((sqrtf(8.f * (float)e + 1.f) - 1.f) * 0.5f);
      while (((rp + 1) * (rp + 2)) >> 1 <= e) ++rp;
      while ((rp * (rp + 1)) >> 1 > e) --rp;
      int cp = e - ((rp * (rp + 1)) >> 1);
      int r = j + 1 + rp, c = j + 1 + cp;
      M[r][c] = fmaf(-M[r][j], M[c][j], M[r][c]);
    }
    __syncthreads();
  }
  if (tid < 64) {               // T = L^{-1}, one lane per column
    int c = tid;
    T[c][c] = 1.f / M[c][c];
    for (int r = c + 1; r < 64; ++r) {
      float s = 0.f;
      for (int t = c; t < r; ++t) s = fmaf(M[r][t], T[t][c], s);
      T[r][c] = -s / M[r][r];
    }
  }
  __syncthreads();
  for (int e = tid; e < 4096; e += 256) {
    int r = e >> 6, c = e & 63;
    LR[a * 4096 + e] = T[r][c];
    LT[a * 4096 + c * 64 + r] = T[r][c];
  }
}

__device__ __forceinline__ void gbar(int* cnt, int target) {
  __syncthreads();
  if (threadIdx.x == 0) {
    __hip_atomic_fetch_add(cnt, 1, __ATOMIC_ACQ_REL, __HIP_MEMORY_SCOPE_AGENT);
    while (__hip_atomic_load(cnt, __ATOMIC_ACQUIRE, __HIP_MEMORY_SCOPE_AGENT) < target) {
      __builtin_amdgcn_s_sleep(2);
    }
  }
  __syncthreads();
}

__device__ __forceinline__ void red_atomic(float v, float* red, float* dst) {
  int tid = threadIdx.x;
  red[tid] = v;
  __syncthreads();
  if (tid < 128) red[tid] += red[tid + 128];
  __syncthreads();
  if (tid < 64) {
    float s = red[tid] + red[tid + 64];
#pragma unroll
    for (int o = 32; o > 0; o >>= 1) s += __shfl_down(s, o, 64);
    if (tid == 0) atomicAdd(dst, s);
  }
  __syncthreads();
}

// z = B_a^{-1} r = Linv^T (Linv r); LT[j*64+k] = Linv[k][j] (u-phase), LR row-major (z-phase)
__device__ __forceinline__ float minv_apply(const float* LTa, const float* LRa,
                                            float* rrow, float* urow, float rl, int lane) {
  rrow[lane] = rl;
  float acc = 0.f;
#pragma unroll 8
  for (int j = 0; j < 64; ++j) acc = fmaf(LTa[j * 64 + lane], rrow[j], acc);
  urow[lane] = acc;
  float z = 0.f;
#pragma unroll 8
  for (int k = 0; k < 64; ++k) z = fmaf(LRa[k * 64 + lane], urow[k], z);
  return z;
}

// ---------------- persistent block-Jacobi PCG, 16 blocks x 256 (thread = (row wv, col lane)) --------
__global__ __launch_bounds__(256) void cg_kernel(const float* RH, const float* GH, const float* H,
                                                 const float* PR, const float* PI,
                                                 const float* LR, const float* LT,
                                                 float* zg, float* xg, int* cnt, float* rz, float* pq) {
  __shared__ float Ps[64][65];
  __shared__ float gsr[4][64];
  __shared__ float prs[4][64], pis[4][64];
  __shared__ float rls[4][64], us[4][64];
  __shared__ float e1s[4][64], srs[4][64], sis[4][64];
  __shared__ float red[256];
  __shared__ float scl[4];
  int tid = threadIdx.x, blk = blockIdx.x;
  int lane = tid & 63, wv = tid >> 6;
  int a = blk * 4 + wv;
  const float* LRa = LR + a * 4096;
  const float* LTa = LT + a * 4096;
  gsr[wv][lane] = GH[a * 64 + lane];
  prs[wv][lane] = PR[a * 64 + lane];
  pis[wv][lane] = PI[a * 64 + lane];
  float rl = RH[a * 64 + lane];
  float zl = minv_apply(LTa, LRa, rls[wv], us[wv], rl, lane);
  astore(&zg[a * 64 + lane], zl);
  red_atomic(rl * zl, red, &rz[0]);
  int bt = 0;
  gbar(cnt, (++bt) * 16);
  float x = 0.f;
  for (int it = 0; it < MAXIT; ++it) {
    if (tid == 0) {
      scl[0] = aload(&rz[it]);
      scl[1] = (it == 0) ? 1.f : aload(&rz[it - 1]);
      scl[2] = aload(&rz[0]);
    }
    __syncthreads();
    float rrold = scl[0];
    if (it > 0 && rrold < 3e-11f * scl[2]) break;
    float beta = (it == 0) ? 0.f : rrold / scl[1];
    if (it == 0) {
      for (int e = tid; e < 4096; e += 256) Ps[e >> 6][e & 63] = aload(&zg[e]);
    } else {
      for (int e = tid; e < 4096; e += 256) Ps[e >> 6][e & 63] = fmaf(beta, Ps[e >> 6][e & 63], aload(&zg[e]));
    }
    __syncthreads();
    // q = op'(p) for own row a
    float accE = 0.f;
#pragma unroll 8
    for (int c2 = 0; c2 < 64; ++c2) accE = fmaf(gsr[wv][c2], Ps[c2][lane], accE);
    e1s[wv][lane] = accE;
    srs[wv][lane] = Ps[a][lane] * prs[wv][lane];
    sis[wv][lane] = Ps[a][lane] * pis[wv][lane];
    float a1 = 0.f, a2 = 0.f, a3 = 0.f;
#pragma unroll 8
    for (int k = 0; k < 64; ++k) {
      float h = H[k * 64 + lane];
      a1 = fmaf(e1s[wv][k], h, a1);
      a2 = fmaf(srs[wv][k], h, a2);
      a3 = fmaf(sis[wv][k], h, a3);
    }
    float qv = a1 + LMB * (prs[wv][lane] * a2 + pis[wv][lane] * a3);
    float pv = Ps[a][lane];
    red_atomic(pv * qv, red, &pq[it]);
    gbar(cnt, (++bt) * 16);
    if (tid == 0) scl[3] = aload(&pq[it]);
    __syncthreads();
    float alpha = rrold / scl[3];
    x = fmaf(alpha, pv, x);
    rl = fmaf(-alpha, qv, rl);
    zl = minv_apply(LTa, LRa, rls[wv], us[wv], rl, lane);
    astore(&zg[a * 64 + lane], zl);
    red_atomic(rl * zl, red, &rz[it + 1]);
    gbar(cnt, (++bt) * 16);
  }
  xg[a * 64 + lane] = x;
}

// ---------------- out C[r][c] = sum_t Mx[c][t] W^[t][r] ----------------
__global__ __launch_bounds__(256) void finish_kernel(const float* xg, const float* Mx, float* out) {
  __shared__ float Mxs[64 * 65];
  __shared__ float Xs[64 * 64];
  int tid = threadIdx.x;
  for (int e = tid; e < 4096; e += 256) {
    Mxs[(e >> 6) * 65 + (e & 63)] = Mx[e];
    Xs[e] = xg[e];
  }
  __syncthreads();
  int c = tid & 63, rw = tid >> 6;
  for (int u = 0; u < 16; ++u) {
    int r = rw * 16 + u;
    float acc = 0.f;
#pragma unroll 8
    for (int t = 0; t < 64; ++t) acc = fmaf(Mxs[c * 65 + t], Xs[t * 64 + r], acc);
    out[r * 64 + c] = acc;
  }
}

extern "C" void kernel_launch(void* const* d_in, const int* in_sizes, int n_in,
                              void* d_out, int out_size, void* d_ws, size_t ws_size,
                              hipStream_t stream) {
  const float* fx = (const float*)d_in[0];
  const float* fy = (const float*)d_in[1];
  const float* ex = (const float*)d_in[2];
  const float* ey = (const float*)d_in[3];
  const float* Px = (const float*)d_in[4];
  const float* Py = (const float*)d_in[5];
  const float* Mx = (const float*)d_in[6];
  const float* My = (const float*)d_in[7];
  float* out = (float*)d_out;
  float* W = (float*)d_ws;

  if (ws_size < (size_t)WS_NEED * sizeof(float)) {
    hipMemsetAsync(d_out, 0, (size_t)out_size * sizeof(float), stream);
    return;
  }

  float* Ap = W + A_OFF;    float* B0 = W + B0_OFF;  float* Bc = W + BC_OFF;
  float* H = W + H_OFF;     float* G = W + G_OFF;    float* GH = W + GH_OFF;
  float* PR = W + PR_OFF;   float* PI = W + PI_OFF;  float* RH = W + RH_OFF;
  float* zg = W + ZG_OFF;   float* xg = W + XG_OFF;
  float* ctrl = W + CTRL_OFF;
  int* cnt = (int*)(W + CTRL_OFF);
  float* rz = W + CTRL_OFF + 64;
  float* pq = W + CTRL_OFF + 224;
  float* LR = W + LR_OFF;   float* LT = W + LT_OFF;

  zero_kernel<<<64, 256, 0, stream>>>(Ap, 16384);               // A and B0 (contiguous)
  proj2_kernel<<<80, 256, 0, stream>>>(Px, fx, Py, fy, Ap, B0);
  prep1_kernel<<<4, 256, 0, stream>>>(Ap, B0, My, ex, ey, Bc, H, G, PR, PI);
  prep2_kernel<<<2, 256, 0, stream>>>(Ap, Bc, Mx, My, G, GH, RH);
  blockchol_kernel<<<64, 256, 0, stream>>>(H, GH, PR, PI, LR, LT, ctrl);
  cg_kernel<<<16, 256, 0, stream>>>(RH, GH, H, PR, PI, LR, LT, zg, xg, cnt, rz, pq);
  finish_kernel<<<1, 256, 0, stream>>>(xg, Mx, out);
}